// Round 2
// baseline (3552.079 us; speedup 1.0000x reference)
//
#include <hip/hip_runtime.h>
#include <hip/hip_bf16.h>

#define THREADS 256
typedef __hip_bfloat16 bf16;

// ---------------- CSR build (group edges by destination) ----------------
__global__ void hist_k(const int* __restrict__ ei, int* __restrict__ cnt, int E, int ET){
  int i = blockIdx.x*THREADS + threadIdx.x;
  if (i >= ET) return;
  int d = (i < E) ? ei[E + i] : (i - E);   // self-loops appended
  atomicAdd(&cnt[d], 1);
}

__global__ void scan1_k(const int* __restrict__ deg, int* __restrict__ off,
                        int* __restrict__ bsum, int n){
  __shared__ int sh[1024];
  int i = blockIdx.x*1024 + threadIdx.x;
  int v = (i < n) ? deg[i] : 0;
  sh[threadIdx.x] = v;
  __syncthreads();
  for (int s = 1; s < 1024; s <<= 1){
    int t = (threadIdx.x >= s) ? sh[threadIdx.x - s] : 0;
    __syncthreads();
    sh[threadIdx.x] += t;
    __syncthreads();
  }
  if (i < n) off[i+1] = sh[threadIdx.x];
  if (threadIdx.x == 1023) bsum[blockIdx.x] = sh[1023];
}

__global__ void scan2_k(int* __restrict__ bsum, int nb){
  __shared__ int sh[256];
  int v = (threadIdx.x < nb) ? bsum[threadIdx.x] : 0;
  sh[threadIdx.x] = v;
  __syncthreads();
  for (int s = 1; s < 256; s <<= 1){
    int t = (threadIdx.x >= s) ? sh[threadIdx.x - s] : 0;
    __syncthreads();
    sh[threadIdx.x] += t;
    __syncthreads();
  }
  if (threadIdx.x < nb) bsum[threadIdx.x] = sh[threadIdx.x] - v;  // exclusive
}

__global__ void scan3_k(int* __restrict__ off, const int* __restrict__ bsum, int n){
  int i = blockIdx.x*1024 + threadIdx.x;
  if (i < n) off[i+1] += bsum[blockIdx.x];
  if (i == 0) off[0] = 0;
}

__global__ void scatter_k(const int* __restrict__ ei, const int* __restrict__ off,
                          int* __restrict__ cur, int* __restrict__ csr, int E, int ET){
  int i = blockIdx.x*THREADS + threadIdx.x;
  if (i >= ET) return;
  int s, d;
  if (i < E){ s = ei[i]; d = ei[E+i]; } else { s = i - E; d = i - E; }
  int p = off[d] + atomicAdd(&cur[d], 1);
  csr[p] = s;
}

// ---------------- h = in @ W  (wave-per-row, f32 accumulate, bf16 out) ----------------
__global__ void __launch_bounds__(256) gemm_k(
    const float* __restrict__ in, const float* __restrict__ W,
    bf16* __restrict__ hout, int n, int K, int COUT)
{
  int wave = threadIdx.x >> 6, lane = threadIdx.x & 63;
  int row = blockIdx.x*4 + wave;
  if (row >= n) return;
  const float* rp = in + (size_t)row * K;
  int c0 = lane, c1 = lane + 64, c2 = lane + 128;
  bool g0 = c0 < COUT, g1 = c1 < COUT, g2 = c2 < COUT;
  float acc0 = 0.f, acc1 = 0.f, acc2 = 0.f;
  #pragma unroll 8
  for (int k = 0; k < K; k++){
    float a = rp[k];                             // wave-broadcast load
    const float* wr = W + (size_t)k * COUT;      // coalesced across lanes, L1/L2-hot
    if (g0) acc0 += a * wr[c0];
    if (g1) acc1 += a * wr[c1];
    if (g2) acc2 += a * wr[c2];
  }
  bf16* op = hout + (size_t)row * COUT;
  if (g0) op[c0] = __float2bfloat16(acc0);
  if (g1) op[c1] = __float2bfloat16(acc1);
  if (g2) op[c2] = __float2bfloat16(acc2);
}

// ---------------- alpha_src / alpha_dst per (node, head) ----------------
__global__ void alpha_k(const bf16* __restrict__ hbuf,
                        const float* __restrict__ as, const float* __restrict__ ad,
                        float* __restrict__ aS, float* __restrict__ aD,
                        int n, int C, int HC)
{
  int idx = blockIdx.x*THREADS + threadIdx.x;
  if (idx >= n*3) return;
  int node = idx / 3, h = idx - node*3;
  const bf16* hp = hbuf + (size_t)node*HC + h*C;
  const float* ap = as + h*C;
  const float* dp = ad + h*C;
  float s = 0.f, d = 0.f;
  for (int c = 0; c < C; c++){
    float v = __bfloat162float(hp[c]);
    s += v * ap[c];
    d += v * dp[c];
  }
  aS[idx] = s; aD[idx] = d;
}

// ---------------- segment softmax + weighted aggregation (wave per dst node) ----------------
__global__ void __launch_bounds__(256) agg_k(
    const int* __restrict__ off, const int* __restrict__ csr,
    const bf16* __restrict__ hbuf,
    const float* __restrict__ aS, const float* __restrict__ aD,
    const float* __restrict__ bias,
    float* __restrict__ outb, int n, int HC, int cshift, int doElu)
{
  int wave = threadIdx.x >> 6, lane = threadIdx.x & 63;
  int node = blockIdx.x*4 + wave;
  if (node >= n) return;
  int e0 = off[node], e1 = off[node+1];
  float ad0 = aD[node*3+0], ad1 = aD[node*3+1], ad2 = aD[node*3+2];
  // pass 1: per-head max (all lanes redundantly; broadcast loads)
  float m0 = -1e30f, m1 = -1e30f, m2 = -1e30f;
  for (int e = e0; e < e1; e++){
    int s = csr[e];
    float x0 = aS[s*3+0] + ad0; x0 = (x0 > 0.f) ? x0 : 0.2f*x0; m0 = fmaxf(m0, x0);
    float x1 = aS[s*3+1] + ad1; x1 = (x1 > 0.f) ? x1 : 0.2f*x1; m1 = fmaxf(m1, x1);
    float x2 = aS[s*3+2] + ad2; x2 = (x2 > 0.f) ? x2 : 0.2f*x2; m2 = fmaxf(m2, x2);
  }
  // pass 2: exp-sum + weighted channel accumulation
  int c0 = lane, c1 = lane + 64, c2 = lane + 128;
  bool g0 = c0 < HC, g1 = c1 < HC, g2 = c2 < HC;
  int h0 = c0 >> cshift, h1 = c1 >> cshift, h2 = c2 >> cshift;
  float d0 = 0.f, d1 = 0.f, d2 = 0.f;
  float acc0 = 0.f, acc1 = 0.f, acc2 = 0.f;
  for (int e = e0; e < e1; e++){
    int s = csr[e];
    float x0 = aS[s*3+0] + ad0; x0 = (x0 > 0.f) ? x0 : 0.2f*x0; float w0 = __expf(x0 - m0);
    float x1 = aS[s*3+1] + ad1; x1 = (x1 > 0.f) ? x1 : 0.2f*x1; float w1 = __expf(x1 - m1);
    float x2 = aS[s*3+2] + ad2; x2 = (x2 > 0.f) ? x2 : 0.2f*x2; float w2 = __expf(x2 - m2);
    d0 += w0; d1 += w1; d2 += w2;
    const bf16* hp = hbuf + (size_t)s * HC;
    if (g0){ float w = (h0 == 0) ? w0 : ((h0 == 1) ? w1 : w2); acc0 += w * __bfloat162float(hp[c0]); }
    if (g1){ float w = (h1 == 0) ? w0 : ((h1 == 1) ? w1 : w2); acc1 += w * __bfloat162float(hp[c1]); }
    if (g2){ float w = (h2 == 0) ? w0 : ((h2 == 1) ? w1 : w2); acc2 += w * __bfloat162float(hp[c2]); }
  }
  d0 += 1e-16f; d1 += 1e-16f; d2 += 1e-16f;
  float* op = outb + (size_t)node * HC;
  if (g0){ float dd = (h0==0)?d0:((h0==1)?d1:d2); float r = acc0/dd + bias[c0];
           if (doElu) r = (r > 0.f) ? r : (__expf(r) - 1.f); op[c0] = r; }
  if (g1){ float dd = (h1==0)?d0:((h1==1)?d1:d2); float r = acc1/dd + bias[c1];
           if (doElu) r = (r > 0.f) ? r : (__expf(r) - 1.f); op[c1] = r; }
  if (g2){ float dd = (h2==0)?d0:((h2==1)?d1:d2); float r = acc2/dd + bias[c2];
           if (doElu) r = (r > 0.f) ? r : (__expf(r) - 1.f); op[c2] = r; }
}

// ---------------- global mean pool + head + loss ----------------
__global__ void pool_cnt_k(const int* __restrict__ batch, int* __restrict__ cntg, int n){
  int i = blockIdx.x*THREADS + threadIdx.x;
  if (i < n) atomicAdd(&cntg[batch[i]], 1);
}

__global__ void pool_acc_k(const float* __restrict__ h3, const int* __restrict__ batch,
                           float* __restrict__ pooled, int n){
  int idx = blockIdx.x*THREADS + threadIdx.x;
  if (idx >= n*48) return;
  int node = idx / 48, col = idx - node*48;
  atomicAdd(&pooled[batch[node]*48 + col], h3[idx]);
}

__global__ void logits_k(const float* __restrict__ pooled, const int* __restrict__ cntg,
                         const float* __restrict__ Wl, const float* __restrict__ bl,
                         const float* __restrict__ y, float* __restrict__ outp,
                         float* __restrict__ lossAcc, int gtot)
{
  int g = blockIdx.x*THREADS + threadIdx.x;
  float lossv = 0.f;
  if (g < gtot){
    float inv = 1.0f / fmaxf((float)cntg[g], 1.0f);
    float logit = bl[0];
    const float* pp = pooled + (size_t)g*48;
    for (int c = 0; c < 48; c++){
      float p = fmaxf(pp[c] * inv, 0.f);     // mean pool + relu
      logit += p * Wl[c];
    }
    outp[g] = 1.f / (1.f + __expf(-logit));
    float t = y[g];
    float sp = (logit > 0.f) ? (logit + log1pf(__expf(-logit))) : log1pf(__expf(logit));
    lossv = sp - t * logit;
  }
  for (int o = 32; o > 0; o >>= 1) lossv += __shfl_down(lossv, o);
  if ((threadIdx.x & 63) == 0) atomicAdd(lossAcc, lossv);
}

__global__ void fin_k(const float* __restrict__ lossAcc, float* __restrict__ outp, int gtot){
  outp[gtot] = lossAcc[0] / (float)gtot;
}

// ---------------- launch ----------------
extern "C" void kernel_launch(void* const* d_in, const int* in_sizes, int n_in,
                              void* d_out, int out_size, void* d_ws, size_t ws_size,
                              hipStream_t stream)
{
  (void)n_in; (void)out_size; (void)ws_size;
  const float* x    = (const float*)d_in[0];
  const float* y    = (const float*)d_in[1];
  const int*  ei    = (const int*)d_in[2];
  const int*  batch = (const int*)d_in[3];
  const float* W1 = (const float*)d_in[4];
  const float* as1= (const float*)d_in[5];
  const float* ad1= (const float*)d_in[6];
  const float* b1 = (const float*)d_in[7];
  const float* W2 = (const float*)d_in[8];
  const float* as2= (const float*)d_in[9];
  const float* ad2= (const float*)d_in[10];
  const float* b2 = (const float*)d_in[11];
  const float* W3 = (const float*)d_in[12];
  const float* as3= (const float*)d_in[13];
  const float* ad3= (const float*)d_in[14];
  const float* b3 = (const float*)d_in[15];
  const float* Wl = (const float*)d_in[16];
  const float* bl = (const float*)d_in[17];
  float* outp = (float*)d_out;

  int Nn = in_sizes[0] / 128;
  int Gg = in_sizes[1];
  int Ee = in_sizes[2] / 2;
  int ET = Ee + Nn;

  char* p = (char*)d_ws;
  auto carve = [&](size_t bytes) -> void* {
    void* r = (void*)p; p += (bytes + 255) & ~(size_t)255; return r;
  };
  int*   off     = (int*)  carve((size_t)(Nn+1)*4);
  int*   cnt     = (int*)  carve((size_t)Nn*4);
  int*   csr     = (int*)  carve((size_t)ET*4);
  int*   bsum    = (int*)  carve(256*4);
  float* aS      = (float*)carve((size_t)Nn*3*4);
  float* aD      = (float*)carve((size_t)Nn*3*4);
  float* pooled  = (float*)carve((size_t)Gg*48*4);
  int*   cntg    = (int*)  carve((size_t)Gg*4);
  float* lossAcc = (float*)carve(4);
  bf16*  bufH    = (bf16*) carve((size_t)Nn*192*2);
  float* bufO    = (float*)carve((size_t)Nn*192*4);

  int NB = (Nn + 1023) / 1024;
  int ebk = (ET + THREADS - 1) / THREADS;

  // CSR by destination
  hipMemsetAsync(cnt, 0, (size_t)Nn*4, stream);
  hist_k<<<ebk, THREADS, 0, stream>>>(ei, cnt, Ee, ET);
  scan1_k<<<NB, 1024, 0, stream>>>(cnt, off, bsum, Nn);
  scan2_k<<<1, 256, 0, stream>>>(bsum, NB);
  scan3_k<<<NB, 1024, 0, stream>>>(off, bsum, Nn);
  hipMemsetAsync(cnt, 0, (size_t)Nn*4, stream);
  scatter_k<<<ebk, THREADS, 0, stream>>>(ei, off, cnt, csr, Ee, ET);

  int gb = (Nn + 3) / 4;
  int ab = (Nn*3 + THREADS - 1) / THREADS;
  // layer 1: 128 -> 3x64
  gemm_k<<<gb, 256, 0, stream>>>(x, W1, bufH, Nn, 128, 192);
  alpha_k<<<ab, THREADS, 0, stream>>>(bufH, as1, ad1, aS, aD, Nn, 64, 192);
  agg_k<<<gb, 256, 0, stream>>>(off, csr, bufH, aS, aD, b1, bufO, Nn, 192, 6, 1);
  // layer 2: 192 -> 3x32
  gemm_k<<<gb, 256, 0, stream>>>(bufO, W2, bufH, Nn, 192, 96);
  alpha_k<<<ab, THREADS, 0, stream>>>(bufH, as2, ad2, aS, aD, Nn, 32, 96);
  agg_k<<<gb, 256, 0, stream>>>(off, csr, bufH, aS, aD, b2, bufO, Nn, 96, 5, 1);
  // layer 3: 96 -> 3x16 (no ELU)
  gemm_k<<<gb, 256, 0, stream>>>(bufO, W3, bufH, Nn, 96, 48);
  alpha_k<<<ab, THREADS, 0, stream>>>(bufH, as3, ad3, aS, aD, Nn, 16, 48);
  agg_k<<<gb, 256, 0, stream>>>(off, csr, bufH, aS, aD, b3, bufO, Nn, 48, 4, 0);
  // mean pool + relu + linear + sigmoid + BCE loss
  hipMemsetAsync(pooled, 0, (size_t)Gg*48*4, stream);
  hipMemsetAsync(cntg, 0, (size_t)Gg*4, stream);
  hipMemsetAsync(lossAcc, 0, 4, stream);
  pool_cnt_k<<<(Nn + THREADS-1)/THREADS, THREADS, 0, stream>>>(batch, cntg, Nn);
  pool_acc_k<<<(Nn*48 + THREADS-1)/THREADS, THREADS, 0, stream>>>(bufO, batch, pooled, Nn);
  logits_k<<<(Gg + THREADS-1)/THREADS, THREADS, 0, stream>>>(pooled, cntg, Wl, bl, y, outp, lossAcc, Gg);
  fin_k<<<1, 1, 0, stream>>>(lossAcc, outp, Gg);
}

// Round 3
// 2004.946 us; speedup vs baseline: 1.7717x; 1.7717x over previous
//
#include <hip/hip_runtime.h>
#include <hip/hip_bf16.h>

#define THREADS 256
typedef __hip_bfloat16 bf16;

typedef __bf16 v8bf __attribute__((ext_vector_type(8)));
typedef float  v4f  __attribute__((ext_vector_type(4)));

// ---------------- CSR build (group edges by destination) ----------------
__global__ void hist_k(const int* __restrict__ ei, int* __restrict__ cnt, int E, int ET){
  int i = blockIdx.x*THREADS + threadIdx.x;
  if (i >= ET) return;
  int d = (i < E) ? ei[E + i] : (i - E);   // self-loops appended
  atomicAdd(&cnt[d], 1);
}

__global__ void scan1_k(const int* __restrict__ deg, int* __restrict__ off,
                        int* __restrict__ bsum, int n){
  __shared__ int sh[1024];
  int i = blockIdx.x*1024 + threadIdx.x;
  int v = (i < n) ? deg[i] : 0;
  sh[threadIdx.x] = v;
  __syncthreads();
  for (int s = 1; s < 1024; s <<= 1){
    int t = (threadIdx.x >= s) ? sh[threadIdx.x - s] : 0;
    __syncthreads();
    sh[threadIdx.x] += t;
    __syncthreads();
  }
  if (i < n) off[i+1] = sh[threadIdx.x];
  if (threadIdx.x == 1023) bsum[blockIdx.x] = sh[1023];
}

__global__ void scan2_k(int* __restrict__ bsum, int nb){
  __shared__ int sh[256];
  int v = (threadIdx.x < nb) ? bsum[threadIdx.x] : 0;
  sh[threadIdx.x] = v;
  __syncthreads();
  for (int s = 1; s < 256; s <<= 1){
    int t = (threadIdx.x >= s) ? sh[threadIdx.x - s] : 0;
    __syncthreads();
    sh[threadIdx.x] += t;
    __syncthreads();
  }
  if (threadIdx.x < nb) bsum[threadIdx.x] = sh[threadIdx.x] - v;  // exclusive
}

__global__ void scan3_k(int* __restrict__ off, const int* __restrict__ bsum, int n){
  int i = blockIdx.x*1024 + threadIdx.x;
  if (i < n) off[i+1] += bsum[blockIdx.x];
  if (i == 0) off[0] = 0;
}

__global__ void scatter_k(const int* __restrict__ ei, const int* __restrict__ off,
                          int* __restrict__ cur, int* __restrict__ csr, int E, int ET){
  int i = blockIdx.x*THREADS + threadIdx.x;
  if (i >= ET) return;
  int s, d;
  if (i < E){ s = ei[i]; d = ei[E+i]; } else { s = i - E; d = i - E; }
  int p = off[d] + atomicAdd(&cur[d], 1);
  csr[p] = s;
}

// ---------------- dtype prep ----------------
__global__ void convf2b_k(const float* __restrict__ in, bf16* __restrict__ out, int n){
  int i = blockIdx.x*THREADS + threadIdx.x;
  if (i < n) out[i] = __float2bfloat16(in[i]);
}

// WT[c*K + k] = bf16(W[k*COUT + c])   (tiny matrices; coalesced reads)
__global__ void wt_k(const float* __restrict__ W, bf16* __restrict__ WT, int K, int COUT){
  int i = blockIdx.x*THREADS + threadIdx.x;
  if (i >= K*COUT) return;
  int k = i / COUT, c = i - k*COUT;
  WT[(size_t)c*K + k] = __float2bfloat16(W[i]);
}

// ---------------- MFMA GEMM: C[n x COUT] = A[n x K] @ B, B given as BT[COUT x K]
// wave = one 16x16 output tile; K multiple of 32; n multiple of 16; COUT multiple of 16.
template<int K>
__global__ void __launch_bounds__(256) gemm_mfma_k(
    const bf16* __restrict__ A, const bf16* __restrict__ BT,
    bf16* __restrict__ C, int nRowTiles, int COUT)
{
  int wave = threadIdx.x >> 6, lane = threadIdx.x & 63;
  int rt = blockIdx.x*4 + wave;
  if (rt >= nRowTiles) return;
  int half = lane & 15;
  int quad = lane >> 4;
  int cb = blockIdx.y * 16;
  const __bf16* aBase = (const __bf16*)A + (size_t)(rt*16 + half)*K + quad*8;
  const __bf16* bBase = (const __bf16*)BT + (size_t)(cb + half)*K + quad*8;
  v4f acc = {0.f, 0.f, 0.f, 0.f};
  #pragma unroll
  for (int k0 = 0; k0 < K; k0 += 32){
    v8bf aF = *(const v8bf*)(aBase + k0);
    v8bf bF = *(const v8bf*)(bBase + k0);
    acc = __builtin_amdgcn_mfma_f32_16x16x32_bf16(aF, bF, acc, 0, 0, 0);
  }
  int orow = rt*16 + quad*4;                 // D: col=lane&15, row=quad*4+reg (m89-verified)
  bf16* cp = C + (size_t)orow*COUT + cb + half;
  #pragma unroll
  for (int r = 0; r < 4; r++)
    cp[(size_t)r*COUT] = __float2bfloat16(acc[r]);
}

// ---------------- alpha_src / alpha_dst per (node, head) ----------------
__global__ void alpha_k(const bf16* __restrict__ hbuf,
                        const float* __restrict__ as, const float* __restrict__ ad,
                        float* __restrict__ aS, float* __restrict__ aD,
                        int n, int C, int HC)
{
  int idx = blockIdx.x*THREADS + threadIdx.x;
  if (idx >= n*3) return;
  int node = idx / 3, h = idx - node*3;
  const bf16* hp = hbuf + (size_t)node*HC + h*C;
  const float* ap = as + h*C;
  const float* dp = ad + h*C;
  float s = 0.f, d = 0.f;
  for (int c = 0; c < C; c++){
    float v = __bfloat162float(hp[c]);
    s += v * ap[c];
    d += v * dp[c];
  }
  aS[idx] = s; aD[idx] = d;
}

// ---------------- segment softmax + weighted aggregation (wave per dst node) ----------------
__global__ void __launch_bounds__(256) agg_k(
    const int* __restrict__ off, const int* __restrict__ csr,
    const bf16* __restrict__ hbuf,
    const float* __restrict__ aS, const float* __restrict__ aD,
    const float* __restrict__ bias,
    float* __restrict__ outF, bf16* __restrict__ outB,
    int n, int HC, int cshift, int doElu)
{
  int wave = threadIdx.x >> 6, lane = threadIdx.x & 63;
  int node = blockIdx.x*4 + wave;
  if (node >= n) return;
  int e0 = off[node], e1 = off[node+1];
  float ad0 = aD[node*3+0], ad1 = aD[node*3+1], ad2 = aD[node*3+2];
  // pass 1: per-head max (all lanes redundantly; broadcast loads)
  float m0 = -1e30f, m1 = -1e30f, m2 = -1e30f;
  for (int e = e0; e < e1; e++){
    int s = csr[e];
    float x0 = aS[s*3+0] + ad0; x0 = (x0 > 0.f) ? x0 : 0.2f*x0; m0 = fmaxf(m0, x0);
    float x1 = aS[s*3+1] + ad1; x1 = (x1 > 0.f) ? x1 : 0.2f*x1; m1 = fmaxf(m1, x1);
    float x2 = aS[s*3+2] + ad2; x2 = (x2 > 0.f) ? x2 : 0.2f*x2; m2 = fmaxf(m2, x2);
  }
  // pass 2: exp-sum + weighted channel accumulation
  int c0 = lane, c1 = lane + 64, c2 = lane + 128;
  bool g0 = c0 < HC, g1 = c1 < HC, g2 = c2 < HC;
  int h0 = c0 >> cshift, h1 = c1 >> cshift, h2 = c2 >> cshift;
  float d0 = 0.f, d1 = 0.f, d2 = 0.f;
  float acc0 = 0.f, acc1 = 0.f, acc2 = 0.f;
  for (int e = e0; e < e1; e++){
    int s = csr[e];
    float x0 = aS[s*3+0] + ad0; x0 = (x0 > 0.f) ? x0 : 0.2f*x0; float w0 = __expf(x0 - m0);
    float x1 = aS[s*3+1] + ad1; x1 = (x1 > 0.f) ? x1 : 0.2f*x1; float w1 = __expf(x1 - m1);
    float x2 = aS[s*3+2] + ad2; x2 = (x2 > 0.f) ? x2 : 0.2f*x2; float w2 = __expf(x2 - m2);
    d0 += w0; d1 += w1; d2 += w2;
    const bf16* hp = hbuf + (size_t)s * HC;
    if (g0){ float w = (h0 == 0) ? w0 : ((h0 == 1) ? w1 : w2); acc0 += w * __bfloat162float(hp[c0]); }
    if (g1){ float w = (h1 == 0) ? w0 : ((h1 == 1) ? w1 : w2); acc1 += w * __bfloat162float(hp[c1]); }
    if (g2){ float w = (h2 == 0) ? w0 : ((h2 == 1) ? w1 : w2); acc2 += w * __bfloat162float(hp[c2]); }
  }
  d0 += 1e-16f; d1 += 1e-16f; d2 += 1e-16f;
  if (g0){ float dd = (h0==0)?d0:((h0==1)?d1:d2); float r = acc0/dd + bias[c0];
           if (doElu) r = (r > 0.f) ? r : (__expf(r) - 1.f);
           if (outF) outF[(size_t)node*HC + c0] = r;
           if (outB) outB[(size_t)node*HC + c0] = __float2bfloat16(r); }
  if (g1){ float dd = (h1==0)?d0:((h1==1)?d1:d2); float r = acc1/dd + bias[c1];
           if (doElu) r = (r > 0.f) ? r : (__expf(r) - 1.f);
           if (outF) outF[(size_t)node*HC + c1] = r;
           if (outB) outB[(size_t)node*HC + c1] = __float2bfloat16(r); }
  if (g2){ float dd = (h2==0)?d0:((h2==1)?d1:d2); float r = acc2/dd + bias[c2];
           if (doElu) r = (r > 0.f) ? r : (__expf(r) - 1.f);
           if (outF) outF[(size_t)node*HC + c2] = r;
           if (outB) outB[(size_t)node*HC + c2] = __float2bfloat16(r); }
}

// ---------------- global mean pool + head + loss ----------------
__global__ void pool_cnt_k(const int* __restrict__ batch, int* __restrict__ cntg, int n){
  int i = blockIdx.x*THREADS + threadIdx.x;
  if (i < n) atomicAdd(&cntg[batch[i]], 1);
}

__global__ void pool_acc_k(const float* __restrict__ h3, const int* __restrict__ batch,
                           float* __restrict__ pooled, int n){
  int idx = blockIdx.x*THREADS + threadIdx.x;
  if (idx >= n*48) return;
  int node = idx / 48, col = idx - node*48;
  atomicAdd(&pooled[batch[node]*48 + col], h3[idx]);
}

__global__ void logits_k(const float* __restrict__ pooled, const int* __restrict__ cntg,
                         const float* __restrict__ Wl, const float* __restrict__ bl,
                         const float* __restrict__ y, float* __restrict__ outp,
                         float* __restrict__ lossAcc, int gtot)
{
  int g = blockIdx.x*THREADS + threadIdx.x;
  float lossv = 0.f;
  if (g < gtot){
    float inv = 1.0f / fmaxf((float)cntg[g], 1.0f);
    float logit = bl[0];
    const float* pp = pooled + (size_t)g*48;
    for (int c = 0; c < 48; c++){
      float p = fmaxf(pp[c] * inv, 0.f);     // mean pool + relu
      logit += p * Wl[c];
    }
    outp[g] = 1.f / (1.f + __expf(-logit));
    float t = y[g];
    float sp = (logit > 0.f) ? (logit + log1pf(__expf(-logit))) : log1pf(__expf(logit));
    lossv = sp - t * logit;
  }
  for (int o = 32; o > 0; o >>= 1) lossv += __shfl_down(lossv, o);
  if ((threadIdx.x & 63) == 0) atomicAdd(lossAcc, lossv);
}

__global__ void fin_k(const float* __restrict__ lossAcc, float* __restrict__ outp, int gtot){
  outp[gtot] = lossAcc[0] / (float)gtot;
}

// ---------------- launch ----------------
extern "C" void kernel_launch(void* const* d_in, const int* in_sizes, int n_in,
                              void* d_out, int out_size, void* d_ws, size_t ws_size,
                              hipStream_t stream)
{
  (void)n_in; (void)out_size; (void)ws_size;
  const float* x    = (const float*)d_in[0];
  const float* y    = (const float*)d_in[1];
  const int*  ei    = (const int*)d_in[2];
  const int*  batch = (const int*)d_in[3];
  const float* W1 = (const float*)d_in[4];
  const float* as1= (const float*)d_in[5];
  const float* ad1= (const float*)d_in[6];
  const float* b1 = (const float*)d_in[7];
  const float* W2 = (const float*)d_in[8];
  const float* as2= (const float*)d_in[9];
  const float* ad2= (const float*)d_in[10];
  const float* b2 = (const float*)d_in[11];
  const float* W3 = (const float*)d_in[12];
  const float* as3= (const float*)d_in[13];
  const float* ad3= (const float*)d_in[14];
  const float* b3 = (const float*)d_in[15];
  const float* Wl = (const float*)d_in[16];
  const float* bl = (const float*)d_in[17];
  float* outp = (float*)d_out;

  int Nn = in_sizes[0] / 128;   // 100000 (multiple of 16)
  int Gg = in_sizes[1];
  int Ee = in_sizes[2] / 2;
  int ET = Ee + Nn;

  char* p = (char*)d_ws;
  auto carve = [&](size_t bytes) -> void* {
    void* r = (void*)p; p += (bytes + 255) & ~(size_t)255; return r;
  };
  int*   off     = (int*)  carve((size_t)(Nn+1)*4);
  int*   cnt     = (int*)  carve((size_t)Nn*4);
  int*   csr     = (int*)  carve((size_t)ET*4);
  int*   bsum    = (int*)  carve(256*4);
  float* aS      = (float*)carve((size_t)Nn*3*4);
  float* aD      = (float*)carve((size_t)Nn*3*4);
  float* pooled  = (float*)carve((size_t)Gg*48*4);
  int*   cntg    = (int*)  carve((size_t)Gg*4);
  float* lossAcc = (float*)carve(4);
  bf16*  WT1     = (bf16*) carve((size_t)192*128*2);
  bf16*  WT2     = (bf16*) carve((size_t)96*192*2);
  bf16*  WT3     = (bf16*) carve((size_t)48*96*2);
  bf16*  bufH    = (bf16*) carve((size_t)Nn*192*2);   // GEMM out (h), agg in
  bf16*  bufA    = (bf16*) carve((size_t)Nn*192*2);   // GEMM A-operand (x, then activated agg out)
  float* bufO    = (float*)carve((size_t)Nn*48*4);    // layer-3 f32 out for pooling

  int NB = (Nn + 1023) / 1024;
  int ebk = (ET + THREADS - 1) / THREADS;

  // CSR by destination
  hipMemsetAsync(cnt, 0, (size_t)Nn*4, stream);
  hist_k<<<ebk, THREADS, 0, stream>>>(ei, cnt, Ee, ET);
  scan1_k<<<NB, 1024, 0, stream>>>(cnt, off, bsum, Nn);
  scan2_k<<<1, 256, 0, stream>>>(bsum, NB);
  scan3_k<<<NB, 1024, 0, stream>>>(off, bsum, Nn);
  hipMemsetAsync(cnt, 0, (size_t)Nn*4, stream);
  scatter_k<<<ebk, THREADS, 0, stream>>>(ei, off, cnt, csr, Ee, ET);

  // dtype prep
  convf2b_k<<<(Nn*128 + THREADS-1)/THREADS, THREADS, 0, stream>>>(x, bufA, Nn*128);
  wt_k<<<(128*192 + THREADS-1)/THREADS, THREADS, 0, stream>>>(W1, WT1, 128, 192);
  wt_k<<<(192*96  + THREADS-1)/THREADS, THREADS, 0, stream>>>(W2, WT2, 192, 96);
  wt_k<<<(96*48   + THREADS-1)/THREADS, THREADS, 0, stream>>>(W3, WT3, 96, 48);

  int nRT = Nn / 16;                 // 6250 row tiles
  int gx  = (nRT + 3) / 4;           // 4 waves/block
  int gb  = (Nn + 3) / 4;
  int ab  = (Nn*3 + THREADS - 1) / THREADS;

  // layer 1: 128 -> 3x64
  gemm_mfma_k<128><<<dim3(gx, 12), 256, 0, stream>>>(bufA, WT1, bufH, nRT, 192);
  alpha_k<<<ab, THREADS, 0, stream>>>(bufH, as1, ad1, aS, aD, Nn, 64, 192);
  agg_k<<<gb, 256, 0, stream>>>(off, csr, bufH, aS, aD, b1, nullptr, bufA, Nn, 192, 6, 1);
  // layer 2: 192 -> 3x32
  gemm_mfma_k<192><<<dim3(gx, 6), 256, 0, stream>>>(bufA, WT2, bufH, nRT, 96);
  alpha_k<<<ab, THREADS, 0, stream>>>(bufH, as2, ad2, aS, aD, Nn, 32, 96);
  agg_k<<<gb, 256, 0, stream>>>(off, csr, bufH, aS, aD, b2, nullptr, bufA, Nn, 96, 5, 1);
  // layer 3: 96 -> 3x16 (no ELU)
  gemm_mfma_k<96><<<dim3(gx, 3), 256, 0, stream>>>(bufA, WT3, bufH, nRT, 48);
  alpha_k<<<ab, THREADS, 0, stream>>>(bufH, as3, ad3, aS, aD, Nn, 16, 48);
  agg_k<<<gb, 256, 0, stream>>>(off, csr, bufH, aS, aD, b3, bufO, nullptr, Nn, 48, 4, 0);

  // mean pool + relu + linear + sigmoid + BCE loss
  hipMemsetAsync(pooled, 0, (size_t)Gg*48*4, stream);
  hipMemsetAsync(cntg, 0, (size_t)Gg*4, stream);
  hipMemsetAsync(lossAcc, 0, 4, stream);
  pool_cnt_k<<<(Nn + THREADS-1)/THREADS, THREADS, 0, stream>>>(batch, cntg, Nn);
  pool_acc_k<<<(Nn*48 + THREADS-1)/THREADS, THREADS, 0, stream>>>(bufO, batch, pooled, Nn);
  logits_k<<<(Gg + THREADS-1)/THREADS, THREADS, 0, stream>>>(pooled, cntg, Wl, bl, y, outp, lossAcc, Gg);
  fin_k<<<1, 1, 0, stream>>>(lossAcc, outp, Gg);
}

// Round 4
// 1188.841 us; speedup vs baseline: 2.9879x; 1.6865x over previous
//
#include <hip/hip_runtime.h>
#include <hip/hip_bf16.h>

#define THREADS 256
typedef __hip_bfloat16 bf16;

typedef __bf16 v8bf __attribute__((ext_vector_type(8)));
typedef float  v4f  __attribute__((ext_vector_type(4)));

__device__ __forceinline__ float bfl(unsigned u){ return __uint_as_float(u << 16); }
__device__ __forceinline__ float bfh(unsigned u){ return __uint_as_float(u & 0xffff0000u); }

// ---------------- CSR build (group edges by destination) ----------------
__global__ void hist_k(const int* __restrict__ ei, int* __restrict__ cnt, int E, int ET){
  int i = blockIdx.x*THREADS + threadIdx.x;
  if (i >= ET) return;
  int d = (i < E) ? ei[E + i] : (i - E);   // self-loops appended
  atomicAdd(&cnt[d], 1);
}

__global__ void scan1_k(const int* __restrict__ deg, int* __restrict__ off,
                        int* __restrict__ bsum, int n){
  __shared__ int sh[1024];
  int i = blockIdx.x*1024 + threadIdx.x;
  int v = (i < n) ? deg[i] : 0;
  sh[threadIdx.x] = v;
  __syncthreads();
  for (int s = 1; s < 1024; s <<= 1){
    int t = (threadIdx.x >= s) ? sh[threadIdx.x - s] : 0;
    __syncthreads();
    sh[threadIdx.x] += t;
    __syncthreads();
  }
  if (i < n) off[i+1] = sh[threadIdx.x];
  if (threadIdx.x == 1023) bsum[blockIdx.x] = sh[1023];
}

__global__ void scan2_k(int* __restrict__ bsum, int nb){
  __shared__ int sh[256];
  int v = (threadIdx.x < nb) ? bsum[threadIdx.x] : 0;
  sh[threadIdx.x] = v;
  __syncthreads();
  for (int s = 1; s < 256; s <<= 1){
    int t = (threadIdx.x >= s) ? sh[threadIdx.x - s] : 0;
    __syncthreads();
    sh[threadIdx.x] += t;
    __syncthreads();
  }
  if (threadIdx.x < nb) bsum[threadIdx.x] = sh[threadIdx.x] - v;  // exclusive
}

__global__ void scan3_k(int* __restrict__ off, const int* __restrict__ bsum, int n){
  int i = blockIdx.x*1024 + threadIdx.x;
  if (i < n) off[i+1] += bsum[blockIdx.x];
  if (i == 0) off[0] = 0;
}

__global__ void scatter_k(const int* __restrict__ ei, const int* __restrict__ off,
                          int* __restrict__ cur, int* __restrict__ csr, int E, int ET){
  int i = blockIdx.x*THREADS + threadIdx.x;
  if (i >= ET) return;
  int s, d;
  if (i < E){ s = ei[i]; d = ei[E+i]; } else { s = i - E; d = i - E; }
  int p = off[d] + atomicAdd(&cur[d], 1);
  csr[p] = s;
}

// ---------------- dtype prep ----------------
__global__ void convf2b_k(const float* __restrict__ in, bf16* __restrict__ out, int n){
  int i = blockIdx.x*THREADS + threadIdx.x;
  if (i < n) out[i] = __float2bfloat16(in[i]);
}

// WT[c*K + k] = bf16(W[k*COUT + c])
__global__ void wt_k(const float* __restrict__ W, bf16* __restrict__ WT, int K, int COUT){
  int i = blockIdx.x*THREADS + threadIdx.x;
  if (i >= K*COUT) return;
  int k = i / COUT, c = i - k*COUT;
  WT[(size_t)c*K + k] = __float2bfloat16(W[i]);
}

// ---------------- MFMA GEMM: C[n x COUT] = A[n x K] @ B (given BT[COUT x K])
// wave = one 16-row tile; A fragments held in regs, loop over all column tiles.
template<int K>
__global__ void __launch_bounds__(256) gemm_mfma_k(
    const bf16* __restrict__ A, const bf16* __restrict__ BT,
    bf16* __restrict__ C, int nRowTiles, int COUT)
{
  int wave = threadIdx.x >> 6, lane = threadIdx.x & 63;
  int rt = blockIdx.x*4 + wave;
  if (rt >= nRowTiles) return;
  int half = lane & 15;
  int quad = lane >> 4;
  const __bf16* aBase = (const __bf16*)A + (size_t)(rt*16 + half)*K + quad*8;
  v8bf aF[K/32];
  #pragma unroll
  for (int kk = 0; kk < K/32; kk++) aF[kk] = *(const v8bf*)(aBase + kk*32);
  for (int cb = 0; cb < COUT; cb += 16){
    const __bf16* bBase = (const __bf16*)BT + (size_t)(cb + half)*K + quad*8;
    v4f acc = {0.f, 0.f, 0.f, 0.f};
    #pragma unroll
    for (int kk = 0; kk < K/32; kk++)
      acc = __builtin_amdgcn_mfma_f32_16x16x32_bf16(aF[kk], *(const v8bf*)(bBase + kk*32), acc, 0, 0, 0);
    int orow = rt*16 + quad*4;                 // D: col=lane&15, row=quad*4+reg
    bf16* cp = C + (size_t)orow*COUT + cb + half;
    #pragma unroll
    for (int r = 0; r < 4; r++)
      cp[(size_t)r*COUT] = __float2bfloat16(acc[r]);
  }
}

// ---------------- alpha_src / alpha_dst per (node, head), stride-4 packed ----------------
__global__ void alpha_k(const bf16* __restrict__ hbuf,
                        const float* __restrict__ as, const float* __restrict__ ad,
                        float* __restrict__ aS4, float* __restrict__ aD4,
                        int n, int C, int HC)
{
  int idx = blockIdx.x*THREADS + threadIdx.x;
  if (idx >= n*3) return;
  int node = idx / 3, h = idx - node*3;
  const bf16* hp = hbuf + (size_t)node*HC + h*C;
  const float* ap = as + h*C;
  const float* dp = ad + h*C;
  float s = 0.f, d = 0.f;
  for (int c = 0; c < C; c++){
    float v = __bfloat162float(hp[c]);
    s += v * ap[c];
    d += v * dp[c];
  }
  aS4[node*4 + h] = s; aD4[node*4 + h] = d;
}

// ---------------- segment softmax + weighted aggregation (wave per dst node) ----------------
// HC = heads*C channels; CSH = log2(C). Lane owns 4 consecutive channels (one head each).
template<int HC, int CSH>
__global__ void __launch_bounds__(256) agg_k(
    const int* __restrict__ off, const int* __restrict__ csr,
    const bf16* __restrict__ hbuf,
    const float* __restrict__ aS4, const float* __restrict__ aD4,
    const float* __restrict__ bias,
    float* __restrict__ outF, bf16* __restrict__ outB,
    int n, int doElu)
{
  int wave = threadIdx.x >> 6, lane = threadIdx.x & 63;
  int node = __builtin_amdgcn_readfirstlane(blockIdx.x*4 + wave);
  if (node >= n) return;
  int e0 = __builtin_amdgcn_readfirstlane(off[node]);
  int e1 = __builtin_amdgcn_readfirstlane(off[node+1]);
  float ad0 = aD4[node*4+0], ad1 = aD4[node*4+1], ad2 = aD4[node*4+2];

  // pass 1: lanes split edges; per-head max, butterfly-reduced across the wave
  float m0 = -1e30f, m1 = -1e30f, m2 = -1e30f;
  for (int e = e0 + lane; e < e1; e += 64){
    int s = csr[e];
    const float4 av = *(const float4*)(aS4 + 4*s);
    float x0 = av.x + ad0; x0 = (x0 > 0.f) ? x0 : 0.2f*x0; m0 = fmaxf(m0, x0);
    float x1 = av.y + ad1; x1 = (x1 > 0.f) ? x1 : 0.2f*x1; m1 = fmaxf(m1, x1);
    float x2 = av.z + ad2; x2 = (x2 > 0.f) ? x2 : 0.2f*x2; m2 = fmaxf(m2, x2);
  }
  #pragma unroll
  for (int o = 32; o > 0; o >>= 1){
    m0 = fmaxf(m0, __shfl_xor(m0, o));
    m1 = fmaxf(m1, __shfl_xor(m1, o));
    m2 = fmaxf(m2, __shfl_xor(m2, o));
  }

  // pass 2: denominators + weighted channel gather (lane q -> channels 4q..4q+3)
  const int q = lane;
  const bool act = q < HC/4;
  const int hq = (4*q) >> CSH;               // head of this lane's channels (compile-time shift)
  float d0 = 0.f, d1 = 0.f, d2 = 0.f;
  float a0 = 0.f, a1 = 0.f, a2 = 0.f, a3 = 0.f;
  for (int e = e0; e < e1; e++){
    int s = __builtin_amdgcn_readfirstlane(csr[e]);   // wave-uniform -> SMEM path
    const float4 av = *(const float4*)(aS4 + 4*s);
    float x0 = av.x + ad0; x0 = (x0 > 0.f) ? x0 : 0.2f*x0; float w0 = __expf(x0 - m0);
    float x1 = av.y + ad1; x1 = (x1 > 0.f) ? x1 : 0.2f*x1; float w1 = __expf(x1 - m1);
    float x2 = av.z + ad2; x2 = (x2 > 0.f) ? x2 : 0.2f*x2; float w2 = __expf(x2 - m2);
    d0 += w0; d1 += w1; d2 += w2;
    if (act){
      uint2 u = *(const uint2*)(hbuf + (size_t)s*HC + 4*q);
      float w = (hq == 0) ? w0 : ((hq == 1) ? w1 : w2);
      a0 += w * bfl(u.x); a1 += w * bfh(u.x);
      a2 += w * bfl(u.y); a3 += w * bfh(u.y);
    }
  }
  if (act){
    float dh = ((hq == 0) ? d0 : ((hq == 1) ? d1 : d2)) + 1e-16f;
    float inv = 1.f / dh;
    const float4 b = *(const float4*)(bias + 4*q);
    float r0 = a0*inv + b.x, r1 = a1*inv + b.y, r2 = a2*inv + b.z, r3 = a3*inv + b.w;
    if (doElu){
      r0 = (r0 > 0.f) ? r0 : (__expf(r0) - 1.f);
      r1 = (r1 > 0.f) ? r1 : (__expf(r1) - 1.f);
      r2 = (r2 > 0.f) ? r2 : (__expf(r2) - 1.f);
      r3 = (r3 > 0.f) ? r3 : (__expf(r3) - 1.f);
    }
    if (outF){
      float4 o = {r0, r1, r2, r3};
      *(float4*)(outF + (size_t)node*HC + 4*q) = o;
    }
    if (outB){
      union { bf16 h[4]; uint2 u; } cv;
      cv.h[0] = __float2bfloat16(r0); cv.h[1] = __float2bfloat16(r1);
      cv.h[2] = __float2bfloat16(r2); cv.h[3] = __float2bfloat16(r3);
      *(uint2*)(outB + (size_t)node*HC + 4*q) = cv.u;
    }
  }
}

// ---------------- global mean pool + head + loss ----------------
__global__ void pool_cnt_k(const int* __restrict__ batch, int* __restrict__ cntg, int n){
  int i = blockIdx.x*THREADS + threadIdx.x;
  if (i < n) atomicAdd(&cntg[batch[i]], 1);
}

__global__ void pool_acc_k(const float* __restrict__ h3, const int* __restrict__ batch,
                           float* __restrict__ pooled, int n){
  int idx = blockIdx.x*THREADS + threadIdx.x;
  if (idx >= n*48) return;
  int node = idx / 48, col = idx - node*48;
  atomicAdd(&pooled[batch[node]*48 + col], h3[idx]);
}

__global__ void logits_k(const float* __restrict__ pooled, const int* __restrict__ cntg,
                         const float* __restrict__ Wl, const float* __restrict__ bl,
                         const float* __restrict__ y, float* __restrict__ outp,
                         float* __restrict__ lossAcc, int gtot)
{
  int g = blockIdx.x*THREADS + threadIdx.x;
  float lossv = 0.f;
  if (g < gtot){
    float inv = 1.0f / fmaxf((float)cntg[g], 1.0f);
    float logit = bl[0];
    const float* pp = pooled + (size_t)g*48;
    for (int c = 0; c < 48; c++){
      float p = fmaxf(pp[c] * inv, 0.f);     // mean pool + relu
      logit += p * Wl[c];
    }
    outp[g] = 1.f / (1.f + __expf(-logit));
    float t = y[g];
    float sp = (logit > 0.f) ? (logit + log1pf(__expf(-logit))) : log1pf(__expf(logit));
    lossv = sp - t * logit;
  }
  for (int o = 32; o > 0; o >>= 1) lossv += __shfl_down(lossv, o);
  if ((threadIdx.x & 63) == 0) atomicAdd(lossAcc, lossv);
}

__global__ void fin_k(const float* __restrict__ lossAcc, float* __restrict__ outp, int gtot){
  outp[gtot] = lossAcc[0] / (float)gtot;
}

// ---------------- launch ----------------
extern "C" void kernel_launch(void* const* d_in, const int* in_sizes, int n_in,
                              void* d_out, int out_size, void* d_ws, size_t ws_size,
                              hipStream_t stream)
{
  (void)n_in; (void)out_size; (void)ws_size;
  const float* x    = (const float*)d_in[0];
  const float* y    = (const float*)d_in[1];
  const int*  ei    = (const int*)d_in[2];
  const int*  batch = (const int*)d_in[3];
  const float* W1 = (const float*)d_in[4];
  const float* as1= (const float*)d_in[5];
  const float* ad1= (const float*)d_in[6];
  const float* b1 = (const float*)d_in[7];
  const float* W2 = (const float*)d_in[8];
  const float* as2= (const float*)d_in[9];
  const float* ad2= (const float*)d_in[10];
  const float* b2 = (const float*)d_in[11];
  const float* W3 = (const float*)d_in[12];
  const float* as3= (const float*)d_in[13];
  const float* ad3= (const float*)d_in[14];
  const float* b3 = (const float*)d_in[15];
  const float* Wl = (const float*)d_in[16];
  const float* bl = (const float*)d_in[17];
  float* outp = (float*)d_out;

  int Nn = in_sizes[0] / 128;   // 100000 (multiple of 16)
  int Gg = in_sizes[1];
  int Ee = in_sizes[2] / 2;
  int ET = Ee + Nn;

  char* p = (char*)d_ws;
  auto carve = [&](size_t bytes) -> void* {
    void* r = (void*)p; p += (bytes + 255) & ~(size_t)255; return r;
  };
  int*   off     = (int*)  carve((size_t)(Nn+1)*4);
  int*   cnt     = (int*)  carve((size_t)Nn*4);
  int*   csr     = (int*)  carve((size_t)ET*4);
  int*   bsum    = (int*)  carve(256*4);
  float* aS4     = (float*)carve((size_t)Nn*4*4);
  float* aD4     = (float*)carve((size_t)Nn*4*4);
  float* pooled  = (float*)carve((size_t)Gg*48*4);
  int*   cntg    = (int*)  carve((size_t)Gg*4);
  float* lossAcc = (float*)carve(4);
  bf16*  WT1     = (bf16*) carve((size_t)192*128*2);
  bf16*  WT2     = (bf16*) carve((size_t)96*192*2);
  bf16*  WT3     = (bf16*) carve((size_t)48*96*2);
  bf16*  bufH    = (bf16*) carve((size_t)Nn*192*2);   // GEMM out (h), agg in
  bf16*  bufA    = (bf16*) carve((size_t)Nn*192*2);   // GEMM A-operand (x, then activated agg out)
  float* bufO    = (float*)carve((size_t)Nn*48*4);    // layer-3 f32 out for pooling

  int NB = (Nn + 1023) / 1024;
  int ebk = (ET + THREADS - 1) / THREADS;

  // CSR by destination
  hipMemsetAsync(cnt, 0, (size_t)Nn*4, stream);
  hist_k<<<ebk, THREADS, 0, stream>>>(ei, cnt, Ee, ET);
  scan1_k<<<NB, 1024, 0, stream>>>(cnt, off, bsum, Nn);
  scan2_k<<<1, 256, 0, stream>>>(bsum, NB);
  scan3_k<<<NB, 1024, 0, stream>>>(off, bsum, Nn);
  hipMemsetAsync(cnt, 0, (size_t)Nn*4, stream);
  scatter_k<<<ebk, THREADS, 0, stream>>>(ei, off, cnt, csr, Ee, ET);

  // dtype prep
  convf2b_k<<<(Nn*128 + THREADS-1)/THREADS, THREADS, 0, stream>>>(x, bufA, Nn*128);
  wt_k<<<(128*192 + THREADS-1)/THREADS, THREADS, 0, stream>>>(W1, WT1, 128, 192);
  wt_k<<<(192*96  + THREADS-1)/THREADS, THREADS, 0, stream>>>(W2, WT2, 192, 96);
  wt_k<<<(96*48   + THREADS-1)/THREADS, THREADS, 0, stream>>>(W3, WT3, 96, 48);

  int nRT = Nn / 16;                 // 6250 row tiles
  int gx  = (nRT + 3) / 4;           // 4 waves/block
  int gb  = (Nn + 3) / 4;
  int ab  = (Nn*3 + THREADS - 1) / THREADS;

  // layer 1: 128 -> 3x64
  gemm_mfma_k<128><<<gx, 256, 0, stream>>>(bufA, WT1, bufH, nRT, 192);
  alpha_k<<<ab, THREADS, 0, stream>>>(bufH, as1, ad1, aS4, aD4, Nn, 64, 192);
  agg_k<192,6><<<gb, 256, 0, stream>>>(off, csr, bufH, aS4, aD4, b1, nullptr, bufA, Nn, 1);
  // layer 2: 192 -> 3x32
  gemm_mfma_k<192><<<gx, 256, 0, stream>>>(bufA, WT2, bufH, nRT, 96);
  alpha_k<<<ab, THREADS, 0, stream>>>(bufH, as2, ad2, aS4, aD4, Nn, 32, 96);
  agg_k<96,5><<<gb, 256, 0, stream>>>(off, csr, bufH, aS4, aD4, b2, nullptr, bufA, Nn, 1);
  // layer 3: 96 -> 3x16 (no ELU)
  gemm_mfma_k<96><<<gx, 256, 0, stream>>>(bufA, WT3, bufH, nRT, 48);
  alpha_k<<<ab, THREADS, 0, stream>>>(bufH, as3, ad3, aS4, aD4, Nn, 16, 48);
  agg_k<48,4><<<gb, 256, 0, stream>>>(off, csr, bufH, aS4, aD4, b3, bufO, nullptr, Nn, 0);

  // mean pool + relu + linear + sigmoid + BCE loss
  hipMemsetAsync(pooled, 0, (size_t)Gg*48*4, stream);
  hipMemsetAsync(cntg, 0, (size_t)Gg*4, stream);
  hipMemsetAsync(lossAcc, 0, 4, stream);
  pool_cnt_k<<<(Nn + THREADS-1)/THREADS, THREADS, 0, stream>>>(batch, cntg, Nn);
  pool_acc_k<<<(Nn*48 + THREADS-1)/THREADS, THREADS, 0, stream>>>(bufO, batch, pooled, Nn);
  logits_k<<<(Gg + THREADS-1)/THREADS, THREADS, 0, stream>>>(pooled, cntg, Wl, bl, y, outp, lossAcc, Gg);
  fin_k<<<1, 1, 0, stream>>>(lossAcc, outp, Gg);
}

// Round 5
// 1160.730 us; speedup vs baseline: 3.0602x; 1.0242x over previous
//
#include <hip/hip_runtime.h>
#include <hip/hip_bf16.h>

#define THREADS 256
typedef __hip_bfloat16 bf16;

typedef __bf16 v8bf __attribute__((ext_vector_type(8)));
typedef float  v4f  __attribute__((ext_vector_type(4)));

__device__ __forceinline__ float bfl(unsigned u){ return __uint_as_float(u << 16); }
__device__ __forceinline__ float bfh(unsigned u){ return __uint_as_float(u & 0xffff0000u); }

// ---------------- CSR build (group edges by destination) ----------------
__global__ void hist_k(const int* __restrict__ ei, int* __restrict__ cnt, int E, int ET){
  int i = blockIdx.x*THREADS + threadIdx.x;
  if (i >= ET) return;
  int d = (i < E) ? ei[E + i] : (i - E);   // self-loops appended
  atomicAdd(&cnt[d], 1);
}

__global__ void scan1_k(const int* __restrict__ deg, int* __restrict__ off,
                        int* __restrict__ bsum, int n){
  __shared__ int sh[1024];
  int i = blockIdx.x*1024 + threadIdx.x;
  int v = (i < n) ? deg[i] : 0;
  sh[threadIdx.x] = v;
  __syncthreads();
  for (int s = 1; s < 1024; s <<= 1){
    int t = (threadIdx.x >= s) ? sh[threadIdx.x - s] : 0;
    __syncthreads();
    sh[threadIdx.x] += t;
    __syncthreads();
  }
  if (i < n) off[i+1] = sh[threadIdx.x];
  if (threadIdx.x == 1023) bsum[blockIdx.x] = sh[1023];
}

__global__ void scan2_k(int* __restrict__ bsum, int nb){
  __shared__ int sh[256];
  int v = (threadIdx.x < nb) ? bsum[threadIdx.x] : 0;
  sh[threadIdx.x] = v;
  __syncthreads();
  for (int s = 1; s < 256; s <<= 1){
    int t = (threadIdx.x >= s) ? sh[threadIdx.x - s] : 0;
    __syncthreads();
    sh[threadIdx.x] += t;
    __syncthreads();
  }
  if (threadIdx.x < nb) bsum[threadIdx.x] = sh[threadIdx.x] - v;  // exclusive
}

__global__ void scan3_k(int* __restrict__ off, const int* __restrict__ bsum, int n){
  int i = blockIdx.x*1024 + threadIdx.x;
  if (i < n) off[i+1] += bsum[blockIdx.x];
  if (i == 0) off[0] = 0;
}

__global__ void scatter_k(const int* __restrict__ ei, const int* __restrict__ off,
                          int* __restrict__ cur, int* __restrict__ csr,
                          int* __restrict__ csrd, int E, int ET){
  int i = blockIdx.x*THREADS + threadIdx.x;
  if (i >= ET) return;
  int s, d;
  if (i < E){ s = ei[i]; d = ei[E+i]; } else { s = i - E; d = i - E; }
  int p = off[d] + atomicAdd(&cur[d], 1);
  csr[p] = s;
  csrd[p] = d;
}

// ---------------- dtype prep ----------------
__global__ void convf2b_k(const float* __restrict__ in, bf16* __restrict__ out, int n){
  int i = blockIdx.x*THREADS + threadIdx.x;
  if (i < n) out[i] = __float2bfloat16(in[i]);
}

// WT[c*K + k] = bf16(W[k*COUT + c])
__global__ void wt_k(const float* __restrict__ W, bf16* __restrict__ WT, int K, int COUT){
  int i = blockIdx.x*THREADS + threadIdx.x;
  if (i >= K*COUT) return;
  int k = i / COUT, c = i - k*COUT;
  WT[(size_t)c*K + k] = __float2bfloat16(W[i]);
}

// ---------------- MFMA GEMM: C[n x COUT] = A[n x K] @ B (given BT[COUT x K])
template<int K>
__global__ void __launch_bounds__(256) gemm_mfma_k(
    const bf16* __restrict__ A, const bf16* __restrict__ BT,
    bf16* __restrict__ C, int nRowTiles, int COUT)
{
  int wave = threadIdx.x >> 6, lane = threadIdx.x & 63;
  int rt = blockIdx.x*4 + wave;
  if (rt >= nRowTiles) return;
  int half = lane & 15;
  int quad = lane >> 4;
  const __bf16* aBase = (const __bf16*)A + (size_t)(rt*16 + half)*K + quad*8;
  v8bf aF[K/32];
  #pragma unroll
  for (int kk = 0; kk < K/32; kk++) aF[kk] = *(const v8bf*)(aBase + kk*32);
  for (int cb = 0; cb < COUT; cb += 16){
    const __bf16* bBase = (const __bf16*)BT + (size_t)(cb + half)*K + quad*8;
    v4f acc = {0.f, 0.f, 0.f, 0.f};
    #pragma unroll
    for (int kk = 0; kk < K/32; kk++)
      acc = __builtin_amdgcn_mfma_f32_16x16x32_bf16(aF[kk], *(const v8bf*)(bBase + kk*32), acc, 0, 0, 0);
    int orow = rt*16 + quad*4;                 // D: col=lane&15, row=quad*4+reg
    bf16* cp = C + (size_t)orow*COUT + cb + half;
    #pragma unroll
    for (int r = 0; r < 4; r++)
      cp[(size_t)r*COUT] = __float2bfloat16(acc[r]);
  }
}

// ---------------- alpha_src / alpha_dst per (node, head), stride-4 packed ----------------
__global__ void alpha_k(const bf16* __restrict__ hbuf,
                        const float* __restrict__ as, const float* __restrict__ ad,
                        float* __restrict__ aS4, float* __restrict__ aD4,
                        int n, int C, int HC)
{
  int idx = blockIdx.x*THREADS + threadIdx.x;
  if (idx >= n*3) return;
  int node = idx / 3, h = idx - node*3;
  const bf16* hp = hbuf + (size_t)node*HC + h*C;
  const float* ap = as + h*C;
  const float* dp = ad + h*C;
  float s = 0.f, d = 0.f;
  for (int c = 0; c < C; c++){
    float v = __bfloat162float(hp[c]);
    s += v * ap[c];
    d += v * dp[c];
  }
  aS4[node*4 + h] = s; aD4[node*4 + h] = d;
}

// ---------------- per-edge softmax numerators (edge-parallel, no max shift) ----------------
__global__ void wgt_k(const int* __restrict__ csr, const int* __restrict__ csrd,
                      const float* __restrict__ aS4, const float* __restrict__ aD4,
                      float* __restrict__ wbuf, int ET)
{
  int i = blockIdx.x*THREADS + threadIdx.x;
  if (i >= ET) return;
  int s = csr[i], d = csrd[i];
  const float4 as = *(const float4*)(aS4 + 4*s);
  const float4 ad = *(const float4*)(aD4 + 4*d);
  float x0 = as.x + ad.x; x0 = (x0 > 0.f) ? x0 : 0.2f*x0;
  float x1 = as.y + ad.y; x1 = (x1 > 0.f) ? x1 : 0.2f*x1;
  float x2 = as.z + ad.z; x2 = (x2 > 0.f) ? x2 : 0.2f*x2;
  float4 w = {__expf(x0), __expf(x1), __expf(x2), 0.f};
  *(float4*)(wbuf + 4*i) = w;
}

// ---------------- weighted aggregation (GRP lanes per dst node) ----------------
// HC channels, CSH = log2(C), GRP lanes/node (HC/4 active); 64/GRP nodes per wave.
template<int HC, int CSH, int GRP>
__global__ void __launch_bounds__(256) agg_k(
    const int* __restrict__ off, const int* __restrict__ csr,
    const bf16* __restrict__ hbuf, const float* __restrict__ wbuf,
    const float* __restrict__ bias,
    float* __restrict__ outF, bf16* __restrict__ outB,
    int n, int doElu)
{
  constexpr int NPW = 64 / GRP;
  int lane = threadIdx.x & 63;
  int wv = (blockIdx.x*256 + threadIdx.x) >> 6;
  int q = lane % GRP;
  int node = wv*NPW + lane/GRP;
  if (node >= n) return;
  int e0 = off[node], e1 = off[node+1];
  const bool act = q < HC/4;
  const int hq = (4*q) >> CSH;               // head of this lane's 4 channels
  float d0 = 0.f, d1 = 0.f, d2 = 0.f;
  float a0 = 0.f, a1 = 0.f, a2 = 0.f, a3 = 0.f;
  for (int e = e0; e < e1; e++){
    int s = csr[e];
    const float4 w4 = *(const float4*)(wbuf + 4*e);
    d0 += w4.x; d1 += w4.y; d2 += w4.z;
    if (act){
      uint2 u = *(const uint2*)(hbuf + (size_t)s*HC + 4*q);
      float w = (hq == 0) ? w4.x : ((hq == 1) ? w4.y : w4.z);
      a0 += w * bfl(u.x); a1 += w * bfh(u.x);
      a2 += w * bfl(u.y); a3 += w * bfh(u.y);
    }
  }
  if (act){
    float dh = ((hq == 0) ? d0 : ((hq == 1) ? d1 : d2)) + 1e-16f;
    float inv = 1.f / dh;
    const float4 b = *(const float4*)(bias + 4*q);
    float r0 = a0*inv + b.x, r1 = a1*inv + b.y, r2 = a2*inv + b.z, r3 = a3*inv + b.w;
    if (doElu){
      r0 = (r0 > 0.f) ? r0 : (__expf(r0) - 1.f);
      r1 = (r1 > 0.f) ? r1 : (__expf(r1) - 1.f);
      r2 = (r2 > 0.f) ? r2 : (__expf(r2) - 1.f);
      r3 = (r3 > 0.f) ? r3 : (__expf(r3) - 1.f);
    }
    if (outF){
      float4 o = {r0, r1, r2, r3};
      *(float4*)(outF + (size_t)node*HC + 4*q) = o;
    }
    if (outB){
      union { bf16 h[4]; uint2 u; } cv;
      cv.h[0] = __float2bfloat16(r0); cv.h[1] = __float2bfloat16(r1);
      cv.h[2] = __float2bfloat16(r2); cv.h[3] = __float2bfloat16(r3);
      *(uint2*)(outB + (size_t)node*HC + 4*q) = cv.u;
    }
  }
}

// ---------------- global mean pool + head + loss ----------------
__global__ void pool_cnt_k(const int* __restrict__ batch, int* __restrict__ cntg, int n){
  int i = blockIdx.x*THREADS + threadIdx.x;
  if (i < n) atomicAdd(&cntg[batch[i]], 1);
}

__global__ void pool_acc_k(const float* __restrict__ h3, const int* __restrict__ batch,
                           float* __restrict__ pooled, int n){
  int idx = blockIdx.x*THREADS + threadIdx.x;
  if (idx >= n*48) return;
  int node = idx / 48, col = idx - node*48;
  atomicAdd(&pooled[batch[node]*48 + col], h3[idx]);
}

__global__ void logits_k(const float* __restrict__ pooled, const int* __restrict__ cntg,
                         const float* __restrict__ Wl, const float* __restrict__ bl,
                         const float* __restrict__ y, float* __restrict__ outp,
                         float* __restrict__ lossAcc, int gtot)
{
  int g = blockIdx.x*THREADS + threadIdx.x;
  float lossv = 0.f;
  if (g < gtot){
    float inv = 1.0f / fmaxf((float)cntg[g], 1.0f);
    float logit = bl[0];
    const float* pp = pooled + (size_t)g*48;
    for (int c = 0; c < 48; c++){
      float p = fmaxf(pp[c] * inv, 0.f);     // mean pool + relu
      logit += p * Wl[c];
    }
    outp[g] = 1.f / (1.f + __expf(-logit));
    float t = y[g];
    float sp = (logit > 0.f) ? (logit + log1pf(__expf(-logit))) : log1pf(__expf(logit));
    lossv = sp - t * logit;
  }
  for (int o = 32; o > 0; o >>= 1) lossv += __shfl_down(lossv, o);
  if ((threadIdx.x & 63) == 0) atomicAdd(lossAcc, lossv);
}

__global__ void fin_k(const float* __restrict__ lossAcc, float* __restrict__ outp, int gtot){
  outp[gtot] = lossAcc[0] / (float)gtot;
}

// ---------------- launch ----------------
extern "C" void kernel_launch(void* const* d_in, const int* in_sizes, int n_in,
                              void* d_out, int out_size, void* d_ws, size_t ws_size,
                              hipStream_t stream)
{
  (void)n_in; (void)out_size; (void)ws_size;
  const float* x    = (const float*)d_in[0];
  const float* y    = (const float*)d_in[1];
  const int*  ei    = (const int*)d_in[2];
  const int*  batch = (const int*)d_in[3];
  const float* W1 = (const float*)d_in[4];
  const float* as1= (const float*)d_in[5];
  const float* ad1= (const float*)d_in[6];
  const float* b1 = (const float*)d_in[7];
  const float* W2 = (const float*)d_in[8];
  const float* as2= (const float*)d_in[9];
  const float* ad2= (const float*)d_in[10];
  const float* b2 = (const float*)d_in[11];
  const float* W3 = (const float*)d_in[12];
  const float* as3= (const float*)d_in[13];
  const float* ad3= (const float*)d_in[14];
  const float* b3 = (const float*)d_in[15];
  const float* Wl = (const float*)d_in[16];
  const float* bl = (const float*)d_in[17];
  float* outp = (float*)d_out;

  int Nn = in_sizes[0] / 128;   // 100000 (multiple of 16)
  int Gg = in_sizes[1];
  int Ee = in_sizes[2] / 2;
  int ET = Ee + Nn;

  char* p = (char*)d_ws;
  auto carve = [&](size_t bytes) -> void* {
    void* r = (void*)p; p += (bytes + 255) & ~(size_t)255; return r;
  };
  int*   off     = (int*)  carve((size_t)(Nn+1)*4);
  int*   cnt     = (int*)  carve((size_t)Nn*4);
  int*   csr     = (int*)  carve((size_t)ET*4);
  int*   csrd    = (int*)  carve((size_t)ET*4);
  float* wbuf    = (float*)carve((size_t)ET*4*4);
  int*   bsum    = (int*)  carve(256*4);
  float* aS4     = (float*)carve((size_t)Nn*4*4);
  float* aD4     = (float*)carve((size_t)Nn*4*4);
  float* pooled  = (float*)carve((size_t)Gg*48*4);
  int*   cntg    = (int*)  carve((size_t)Gg*4);
  float* lossAcc = (float*)carve(4);
  bf16*  WT1     = (bf16*) carve((size_t)192*128*2);
  bf16*  WT2     = (bf16*) carve((size_t)96*192*2);
  bf16*  WT3     = (bf16*) carve((size_t)48*96*2);
  bf16*  bufH    = (bf16*) carve((size_t)Nn*192*2);   // GEMM out (h), agg in
  bf16*  bufA    = (bf16*) carve((size_t)Nn*192*2);   // GEMM A-operand
  // layer-3 f32 out for pooling: alias into the unused tail of bufH's region
  // (layer 3 uses only the first Nn*48 bf16 = Nn*96 bytes of bufH)
  float* bufO    = (float*)((char*)bufH + ((size_t)Nn*96 + 255 & ~(size_t)255));

  int NB = (Nn + 1023) / 1024;
  int ebk = (ET + THREADS - 1) / THREADS;

  // CSR by destination
  hipMemsetAsync(cnt, 0, (size_t)Nn*4, stream);
  hist_k<<<ebk, THREADS, 0, stream>>>(ei, cnt, Ee, ET);
  scan1_k<<<NB, 1024, 0, stream>>>(cnt, off, bsum, Nn);
  scan2_k<<<1, 256, 0, stream>>>(bsum, NB);
  scan3_k<<<NB, 1024, 0, stream>>>(off, bsum, Nn);
  hipMemsetAsync(cnt, 0, (size_t)Nn*4, stream);
  scatter_k<<<ebk, THREADS, 0, stream>>>(ei, off, cnt, csr, csrd, Ee, ET);

  // dtype prep
  convf2b_k<<<(Nn*128 + THREADS-1)/THREADS, THREADS, 0, stream>>>(x, bufA, Nn*128);
  wt_k<<<(128*192 + THREADS-1)/THREADS, THREADS, 0, stream>>>(W1, WT1, 128, 192);
  wt_k<<<(192*96  + THREADS-1)/THREADS, THREADS, 0, stream>>>(W2, WT2, 192, 96);
  wt_k<<<(96*48   + THREADS-1)/THREADS, THREADS, 0, stream>>>(W3, WT3, 96, 48);

  int nRT = Nn / 16;                 // 6250 row tiles
  int gx  = (nRT + 3) / 4;           // 4 waves/block
  int ab  = (Nn*3 + THREADS - 1) / THREADS;
  int gb1 = (Nn + 3) / 4;            // GRP=64: 1 node/wave, 4 nodes/block
  int gb2 = (Nn + 7) / 8;            // GRP=32: 2 nodes/wave
  int gb3 = (Nn + 15) / 16;          // GRP=16: 4 nodes/wave

  // layer 1: 128 -> 3x64
  gemm_mfma_k<128><<<gx, 256, 0, stream>>>(bufA, WT1, bufH, nRT, 192);
  alpha_k<<<ab, THREADS, 0, stream>>>(bufH, as1, ad1, aS4, aD4, Nn, 64, 192);
  wgt_k<<<ebk, THREADS, 0, stream>>>(csr, csrd, aS4, aD4, wbuf, ET);
  agg_k<192,6,64><<<gb1, 256, 0, stream>>>(off, csr, bufH, wbuf, b1, nullptr, bufA, Nn, 1);
  // layer 2: 192 -> 3x32
  gemm_mfma_k<192><<<gx, 256, 0, stream>>>(bufA, WT2, bufH, nRT, 96);
  alpha_k<<<ab, THREADS, 0, stream>>>(bufH, as2, ad2, aS4, aD4, Nn, 32, 96);
  wgt_k<<<ebk, THREADS, 0, stream>>>(csr, csrd, aS4, aD4, wbuf, ET);
  agg_k<96,5,32><<<gb2, 256, 0, stream>>>(off, csr, bufH, wbuf, b2, nullptr, bufA, Nn, 1);
  // layer 3: 96 -> 3x16 (no ELU)
  gemm_mfma_k<96><<<gx, 256, 0, stream>>>(bufA, WT3, bufH, nRT, 48);
  alpha_k<<<ab, THREADS, 0, stream>>>(bufH, as3, ad3, aS4, aD4, Nn, 16, 48);
  wgt_k<<<ebk, THREADS, 0, stream>>>(csr, csrd, aS4, aD4, wbuf, ET);
  agg_k<48,4,16><<<gb3, 256, 0, stream>>>(off, csr, bufH, wbuf, b3, bufO, nullptr, Nn, 0);

  // mean pool + relu + linear + sigmoid + BCE loss
  hipMemsetAsync(pooled, 0, (size_t)Gg*48*4, stream);
  hipMemsetAsync(cntg, 0, (size_t)Gg*4, stream);
  hipMemsetAsync(lossAcc, 0, 4, stream);
  pool_cnt_k<<<(Nn + THREADS-1)/THREADS, THREADS, 0, stream>>>(batch, cntg, Nn);
  pool_acc_k<<<(Nn*48 + THREADS-1)/THREADS, THREADS, 0, stream>>>(bufO, batch, pooled, Nn);
  logits_k<<<(Gg + THREADS-1)/THREADS, THREADS, 0, stream>>>(pooled, cntg, Wl, bl, y, outp, lossAcc, Gg);
  fin_k<<<1, 1, 0, stream>>>(lossAcc, outp, Gg);
}

// Round 6
// 854.001 us; speedup vs baseline: 4.1593x; 1.3592x over previous
//
#include <hip/hip_runtime.h>
#include <hip/hip_bf16.h>

#define THREADS 256
typedef __hip_bfloat16 bf16;

typedef __bf16 v8bf __attribute__((ext_vector_type(8)));
typedef float  v4f  __attribute__((ext_vector_type(4)));

__device__ __forceinline__ float bfl(unsigned u){ return __uint_as_float(u << 16); }
__device__ __forceinline__ float bfh(unsigned u){ return __uint_as_float(u & 0xffff0000u); }

// ---------------- CSR build (group edges by destination) ----------------
__global__ void hist_k(const int* __restrict__ ei, int* __restrict__ cnt, int E, int ET){
  int i = blockIdx.x*THREADS + threadIdx.x;
  if (i >= ET) return;
  int d = (i < E) ? ei[E + i] : (i - E);   // self-loops appended
  atomicAdd(&cnt[d], 1);
}

__global__ void scan1_k(const int* __restrict__ deg, int* __restrict__ off,
                        int* __restrict__ bsum, int n){
  __shared__ int sh[1024];
  int i = blockIdx.x*1024 + threadIdx.x;
  int v = (i < n) ? deg[i] : 0;
  sh[threadIdx.x] = v;
  __syncthreads();
  for (int s = 1; s < 1024; s <<= 1){
    int t = (threadIdx.x >= s) ? sh[threadIdx.x - s] : 0;
    __syncthreads();
    sh[threadIdx.x] += t;
    __syncthreads();
  }
  if (i < n) off[i+1] = sh[threadIdx.x];
  if (threadIdx.x == 1023) bsum[blockIdx.x] = sh[1023];
}

__global__ void scan2_k(int* __restrict__ bsum, int nb){
  __shared__ int sh[256];
  int v = (threadIdx.x < nb) ? bsum[threadIdx.x] : 0;
  sh[threadIdx.x] = v;
  __syncthreads();
  for (int s = 1; s < 256; s <<= 1){
    int t = (threadIdx.x >= s) ? sh[threadIdx.x - s] : 0;
    __syncthreads();
    sh[threadIdx.x] += t;
    __syncthreads();
  }
  if (threadIdx.x < nb) bsum[threadIdx.x] = sh[threadIdx.x] - v;  // exclusive
}

__global__ void scan3_k(int* __restrict__ off, const int* __restrict__ bsum, int n){
  int i = blockIdx.x*1024 + threadIdx.x;
  if (i < n) off[i+1] += bsum[blockIdx.x];
  if (i == 0) off[0] = 0;
}

__global__ void scatter_k(const int* __restrict__ ei, const int* __restrict__ off,
                          int* __restrict__ cur, int* __restrict__ csr,
                          int* __restrict__ csrd, int E, int ET){
  int i = blockIdx.x*THREADS + threadIdx.x;
  if (i >= ET) return;
  int s, d;
  if (i < E){ s = ei[i]; d = ei[E+i]; } else { s = i - E; d = i - E; }
  int p = off[d] + atomicAdd(&cur[d], 1);
  csr[p] = s;
  csrd[p] = d;
}

// ---------------- dtype prep ----------------
__global__ void convf2b_k(const float* __restrict__ in, bf16* __restrict__ out, int n){
  int i = blockIdx.x*THREADS + threadIdx.x;
  if (i < n) out[i] = __float2bfloat16(in[i]);
}

// WT[c*K + k] = bf16(W[k*COUT + c])
__global__ void wt_k(const float* __restrict__ W, bf16* __restrict__ WT, int K, int COUT){
  int i = blockIdx.x*THREADS + threadIdx.x;
  if (i >= K*COUT) return;
  int k = i / COUT, c = i - k*COUT;
  WT[(size_t)c*K + k] = __float2bfloat16(W[i]);
}

// ---------------- MFMA GEMM: C[n x COUT] = A[n x K] @ B (given BT[COUT x K])
template<int K>
__global__ void __launch_bounds__(256) gemm_mfma_k(
    const bf16* __restrict__ A, const bf16* __restrict__ BT,
    bf16* __restrict__ C, int nRowTiles, int COUT)
{
  int wave = threadIdx.x >> 6, lane = threadIdx.x & 63;
  int rt = blockIdx.x*4 + wave;
  if (rt >= nRowTiles) return;
  int half = lane & 15;
  int quad = lane >> 4;
  const __bf16* aBase = (const __bf16*)A + (size_t)(rt*16 + half)*K + quad*8;
  v8bf aF[K/32];
  #pragma unroll
  for (int kk = 0; kk < K/32; kk++) aF[kk] = *(const v8bf*)(aBase + kk*32);
  for (int cb = 0; cb < COUT; cb += 16){
    const __bf16* bBase = (const __bf16*)BT + (size_t)(cb + half)*K + quad*8;
    v4f acc = {0.f, 0.f, 0.f, 0.f};
    #pragma unroll
    for (int kk = 0; kk < K/32; kk++)
      acc = __builtin_amdgcn_mfma_f32_16x16x32_bf16(aF[kk], *(const v8bf*)(bBase + kk*32), acc, 0, 0, 0);
    int orow = rt*16 + quad*4;                 // D: col=lane&15, row=quad*4+reg
    bf16* cp = C + (size_t)orow*COUT + cb + half;
    #pragma unroll
    for (int r = 0; r < 4; r++)
      cp[(size_t)r*COUT] = __float2bfloat16(acc[r]);
  }
}

// ---------------- alpha_src / alpha_dst per (node, head), stride-4 packed ----------------
// 16 B vector loads of h; as/ad rows are tiny and L1-hot.
__global__ void alpha_k(const bf16* __restrict__ hbuf,
                        const float* __restrict__ as, const float* __restrict__ ad,
                        float* __restrict__ aS4, float* __restrict__ aD4,
                        int n, int C, int HC)
{
  int idx = blockIdx.x*THREADS + threadIdx.x;
  if (idx >= n*3) return;
  int node = idx / 3, h = idx - node*3;
  const bf16* hp = hbuf + (size_t)node*HC + h*C;
  const float* ap = as + h*C;
  const float* dp = ad + h*C;
  float s = 0.f, d = 0.f;
  for (int c8 = 0; c8 < C; c8 += 8){
    uint4 u = *(const uint4*)(hp + c8);
    float f0 = bfl(u.x), f1 = bfh(u.x), f2 = bfl(u.y), f3 = bfh(u.y);
    float f4 = bfl(u.z), f5 = bfh(u.z), f6 = bfl(u.w), f7 = bfh(u.w);
    s += f0*ap[c8+0] + f1*ap[c8+1] + f2*ap[c8+2] + f3*ap[c8+3]
       + f4*ap[c8+4] + f5*ap[c8+5] + f6*ap[c8+6] + f7*ap[c8+7];
    d += f0*dp[c8+0] + f1*dp[c8+1] + f2*dp[c8+2] + f3*dp[c8+3]
       + f4*dp[c8+4] + f5*dp[c8+5] + f6*dp[c8+6] + f7*dp[c8+7];
  }
  aS4[node*4 + h] = s; aD4[node*4 + h] = d;
}

// ---------------- per-edge softmax numerators (edge-parallel, no max shift) ----------------
__global__ void wgt_k(const int* __restrict__ csr, const int* __restrict__ csrd,
                      const float* __restrict__ aS4, const float* __restrict__ aD4,
                      float* __restrict__ wbuf, int ET)
{
  int i = blockIdx.x*THREADS + threadIdx.x;
  if (i >= ET) return;
  int s = csr[i], d = csrd[i];
  const float4 as = *(const float4*)(aS4 + 4*s);
  const float4 ad = *(const float4*)(aD4 + 4*d);
  float x0 = as.x + ad.x; x0 = (x0 > 0.f) ? x0 : 0.2f*x0;
  float x1 = as.y + ad.y; x1 = (x1 > 0.f) ? x1 : 0.2f*x1;
  float x2 = as.z + ad.z; x2 = (x2 > 0.f) ? x2 : 0.2f*x2;
  float4 w = {__expf(x0), __expf(x1), __expf(x2), 0.f};
  *(float4*)(wbuf + 4*i) = w;
}

// ---------------- weighted aggregation (GRP lanes per dst node) ----------------
// HC channels, CSH = log2(C), GRP lanes/node (HC/4 active); 64/GRP nodes per wave.
// Edge loop unrolled x4: 4 independent gathers in flight per lane (latency hiding).
template<int HC, int CSH, int GRP>
__global__ void __launch_bounds__(256) agg_k(
    const int* __restrict__ off, const int* __restrict__ csr,
    const bf16* __restrict__ hbuf, const float* __restrict__ wbuf,
    const float* __restrict__ bias,
    float* __restrict__ outF, bf16* __restrict__ outB,
    int n, int doElu)
{
  constexpr int NPW = 64 / GRP;
  int lane = threadIdx.x & 63;
  int wv = (blockIdx.x*256 + threadIdx.x) >> 6;
  int q = lane % GRP;
  int node = wv*NPW + lane/GRP;
  if (node >= n) return;
  int e0 = off[node], e1 = off[node+1];
  const bool act = q < HC/4;
  const int hq = (4*q) >> CSH;               // head of this lane's 4 channels
  float d0 = 0.f, d1 = 0.f, d2 = 0.f;
  float a0 = 0.f, a1 = 0.f, a2 = 0.f, a3 = 0.f;
  const size_t hoff = 4*q;
  int e = e0;
  for (; e + 4 <= e1; e += 4){
    int s0 = csr[e+0], s1 = csr[e+1], s2 = csr[e+2], s3 = csr[e+3];
    float4 wA = *(const float4*)(wbuf + 4*(e+0));
    float4 wB = *(const float4*)(wbuf + 4*(e+1));
    float4 wC = *(const float4*)(wbuf + 4*(e+2));
    float4 wD = *(const float4*)(wbuf + 4*(e+3));
    d0 += wA.x + wB.x + wC.x + wD.x;
    d1 += wA.y + wB.y + wC.y + wD.y;
    d2 += wA.z + wB.z + wC.z + wD.z;
    if (act){
      uint2 u0 = *(const uint2*)(hbuf + (size_t)s0*HC + hoff);
      uint2 u1 = *(const uint2*)(hbuf + (size_t)s1*HC + hoff);
      uint2 u2 = *(const uint2*)(hbuf + (size_t)s2*HC + hoff);
      uint2 u3 = *(const uint2*)(hbuf + (size_t)s3*HC + hoff);
      float w0 = (hq == 0) ? wA.x : ((hq == 1) ? wA.y : wA.z);
      float w1 = (hq == 0) ? wB.x : ((hq == 1) ? wB.y : wB.z);
      float w2 = (hq == 0) ? wC.x : ((hq == 1) ? wC.y : wC.z);
      float w3 = (hq == 0) ? wD.x : ((hq == 1) ? wD.y : wD.z);
      a0 += w0*bfl(u0.x); a1 += w0*bfh(u0.x); a2 += w0*bfl(u0.y); a3 += w0*bfh(u0.y);
      a0 += w1*bfl(u1.x); a1 += w1*bfh(u1.x); a2 += w1*bfl(u1.y); a3 += w1*bfh(u1.y);
      a0 += w2*bfl(u2.x); a1 += w2*bfh(u2.x); a2 += w2*bfl(u2.y); a3 += w2*bfh(u2.y);
      a0 += w3*bfl(u3.x); a1 += w3*bfh(u3.x); a2 += w3*bfl(u3.y); a3 += w3*bfh(u3.y);
    }
  }
  for (; e < e1; e++){
    int s = csr[e];
    const float4 w4 = *(const float4*)(wbuf + 4*e);
    d0 += w4.x; d1 += w4.y; d2 += w4.z;
    if (act){
      uint2 u = *(const uint2*)(hbuf + (size_t)s*HC + hoff);
      float w = (hq == 0) ? w4.x : ((hq == 1) ? w4.y : w4.z);
      a0 += w*bfl(u.x); a1 += w*bfh(u.x); a2 += w*bfl(u.y); a3 += w*bfh(u.y);
    }
  }
  if (act){
    float dh = ((hq == 0) ? d0 : ((hq == 1) ? d1 : d2)) + 1e-16f;
    float inv = 1.f / dh;
    const float4 b = *(const float4*)(bias + 4*q);
    float r0 = a0*inv + b.x, r1 = a1*inv + b.y, r2 = a2*inv + b.z, r3 = a3*inv + b.w;
    if (doElu){
      r0 = (r0 > 0.f) ? r0 : (__expf(r0) - 1.f);
      r1 = (r1 > 0.f) ? r1 : (__expf(r1) - 1.f);
      r2 = (r2 > 0.f) ? r2 : (__expf(r2) - 1.f);
      r3 = (r3 > 0.f) ? r3 : (__expf(r3) - 1.f);
    }
    if (outF){
      float4 o = {r0, r1, r2, r3};
      *(float4*)(outF + (size_t)node*HC + 4*q) = o;
    }
    if (outB){
      union { bf16 h[4]; uint2 u; } cv;
      cv.h[0] = __float2bfloat16(r0); cv.h[1] = __float2bfloat16(r1);
      cv.h[2] = __float2bfloat16(r2); cv.h[3] = __float2bfloat16(r3);
      *(uint2*)(outB + (size_t)node*HC + 4*q) = cv.u;
    }
  }
}

// ---------------- global mean pool + head + loss ----------------
__global__ void pool_cnt_k(const int* __restrict__ batch, int* __restrict__ cntg, int n){
  int i = blockIdx.x*THREADS + threadIdx.x;
  if (i < n) atomicAdd(&cntg[batch[i]], 1);
}

__global__ void pool_acc_k(const float* __restrict__ h3, const int* __restrict__ batch,
                           float* __restrict__ pooled, int n){
  int idx = blockIdx.x*THREADS + threadIdx.x;
  if (idx >= n*48) return;
  int node = idx / 48, col = idx - node*48;
  atomicAdd(&pooled[batch[node]*48 + col], h3[idx]);
}

__global__ void logits_k(const float* __restrict__ pooled, const int* __restrict__ cntg,
                         const float* __restrict__ Wl, const float* __restrict__ bl,
                         const float* __restrict__ y, float* __restrict__ outp,
                         float* __restrict__ lossAcc, int gtot)
{
  int g = blockIdx.x*THREADS + threadIdx.x;
  float lossv = 0.f;
  if (g < gtot){
    float inv = 1.0f / fmaxf((float)cntg[g], 1.0f);
    float logit = bl[0];
    const float* pp = pooled + (size_t)g*48;
    for (int c = 0; c < 48; c++){
      float p = fmaxf(pp[c] * inv, 0.f);     // mean pool + relu
      logit += p * Wl[c];
    }
    outp[g] = 1.f / (1.f + __expf(-logit));
    float t = y[g];
    float sp = (logit > 0.f) ? (logit + log1pf(__expf(-logit))) : log1pf(__expf(logit));
    lossv = sp - t * logit;
  }
  for (int o = 32; o > 0; o >>= 1) lossv += __shfl_down(lossv, o);
  if ((threadIdx.x & 63) == 0) atomicAdd(lossAcc, lossv);
}

__global__ void fin_k(const float* __restrict__ lossAcc, float* __restrict__ outp, int gtot){
  outp[gtot] = lossAcc[0] / (float)gtot;
}

// ---------------- launch ----------------
extern "C" void kernel_launch(void* const* d_in, const int* in_sizes, int n_in,
                              void* d_out, int out_size, void* d_ws, size_t ws_size,
                              hipStream_t stream)
{
  (void)n_in; (void)out_size; (void)ws_size;
  const float* x    = (const float*)d_in[0];
  const float* y    = (const float*)d_in[1];
  const int*  ei    = (const int*)d_in[2];
  const int*  batch = (const int*)d_in[3];
  const float* W1 = (const float*)d_in[4];
  const float* as1= (const float*)d_in[5];
  const float* ad1= (const float*)d_in[6];
  const float* b1 = (const float*)d_in[7];
  const float* W2 = (const float*)d_in[8];
  const float* as2= (const float*)d_in[9];
  const float* ad2= (const float*)d_in[10];
  const float* b2 = (const float*)d_in[11];
  const float* W3 = (const float*)d_in[12];
  const float* as3= (const float*)d_in[13];
  const float* ad3= (const float*)d_in[14];
  const float* b3 = (const float*)d_in[15];
  const float* Wl = (const float*)d_in[16];
  const float* bl = (const float*)d_in[17];
  float* outp = (float*)d_out;

  int Nn = in_sizes[0] / 128;   // 100000 (multiple of 16)
  int Gg = in_sizes[1];
  int Ee = in_sizes[2] / 2;
  int ET = Ee + Nn;

  char* p = (char*)d_ws;
  auto carve = [&](size_t bytes) -> void* {
    void* r = (void*)p; p += (bytes + 255) & ~(size_t)255; return r;
  };
  int*   off     = (int*)  carve((size_t)(Nn+1)*4);
  int*   cnt     = (int*)  carve((size_t)Nn*4);
  int*   csr     = (int*)  carve((size_t)ET*4);
  int*   csrd    = (int*)  carve((size_t)ET*4);
  float* wbuf    = (float*)carve((size_t)ET*4*4);
  int*   bsum    = (int*)  carve(256*4);
  float* aS4     = (float*)carve((size_t)Nn*4*4);
  float* aD4     = (float*)carve((size_t)Nn*4*4);
  float* pooled  = (float*)carve((size_t)Gg*48*4);
  int*   cntg    = (int*)  carve((size_t)Gg*4);
  float* lossAcc = (float*)carve(4);
  bf16*  WT1     = (bf16*) carve((size_t)192*128*2);
  bf16*  WT2     = (bf16*) carve((size_t)96*192*2);
  bf16*  WT3     = (bf16*) carve((size_t)48*96*2);
  bf16*  bufH    = (bf16*) carve((size_t)Nn*192*2);   // GEMM out (h), agg in
  bf16*  bufA    = (bf16*) carve((size_t)Nn*192*2);   // GEMM A-operand
  // layer-3 f32 out for pooling: alias into the unused tail of bufH's region
  float* bufO    = (float*)((char*)bufH + ((size_t)Nn*96 + 255 & ~(size_t)255));

  int NB = (Nn + 1023) / 1024;
  int ebk = (ET + THREADS - 1) / THREADS;

  // CSR by destination
  hipMemsetAsync(cnt, 0, (size_t)Nn*4, stream);
  hist_k<<<ebk, THREADS, 0, stream>>>(ei, cnt, Ee, ET);
  scan1_k<<<NB, 1024, 0, stream>>>(cnt, off, bsum, Nn);
  scan2_k<<<1, 256, 0, stream>>>(bsum, NB);
  scan3_k<<<NB, 1024, 0, stream>>>(off, bsum, Nn);
  hipMemsetAsync(cnt, 0, (size_t)Nn*4, stream);
  scatter_k<<<ebk, THREADS, 0, stream>>>(ei, off, cnt, csr, csrd, Ee, ET);

  // dtype prep
  convf2b_k<<<(Nn*128 + THREADS-1)/THREADS, THREADS, 0, stream>>>(x, bufA, Nn*128);
  wt_k<<<(128*192 + THREADS-1)/THREADS, THREADS, 0, stream>>>(W1, WT1, 128, 192);
  wt_k<<<(192*96  + THREADS-1)/THREADS, THREADS, 0, stream>>>(W2, WT2, 192, 96);
  wt_k<<<(96*48   + THREADS-1)/THREADS, THREADS, 0, stream>>>(W3, WT3, 96, 48);

  int nRT = Nn / 16;                 // 6250 row tiles
  int gx  = (nRT + 3) / 4;           // 4 waves/block
  int ab  = (Nn*3 + THREADS - 1) / THREADS;
  int gb1 = (Nn + 3) / 4;            // GRP=64: 1 node/wave
  int gb2 = (Nn + 7) / 8;            // GRP=32: 2 nodes/wave
  int gb3 = (Nn + 15) / 16;          // GRP=16: 4 nodes/wave

  // layer 1: 128 -> 3x64
  gemm_mfma_k<128><<<gx, 256, 0, stream>>>(bufA, WT1, bufH, nRT, 192);
  alpha_k<<<ab, THREADS, 0, stream>>>(bufH, as1, ad1, aS4, aD4, Nn, 64, 192);
  wgt_k<<<ebk, THREADS, 0, stream>>>(csr, csrd, aS4, aD4, wbuf, ET);
  agg_k<192,6,64><<<gb1, 256, 0, stream>>>(off, csr, bufH, wbuf, b1, nullptr, bufA, Nn, 1);
  // layer 2: 192 -> 3x32
  gemm_mfma_k<192><<<gx, 256, 0, stream>>>(bufA, WT2, bufH, nRT, 96);
  alpha_k<<<ab, THREADS, 0, stream>>>(bufH, as2, ad2, aS4, aD4, Nn, 32, 96);
  wgt_k<<<ebk, THREADS, 0, stream>>>(csr, csrd, aS4, aD4, wbuf, ET);
  agg_k<96,5,32><<<gb2, 256, 0, stream>>>(off, csr, bufH, wbuf, b2, nullptr, bufA, Nn, 1);
  // layer 3: 96 -> 3x16 (no ELU)
  gemm_mfma_k<96><<<gx, 256, 0, stream>>>(bufA, WT3, bufH, nRT, 48);
  alpha_k<<<ab, THREADS, 0, stream>>>(bufH, as3, ad3, aS4, aD4, Nn, 16, 48);
  wgt_k<<<ebk, THREADS, 0, stream>>>(csr, csrd, aS4, aD4, wbuf, ET);
  agg_k<48,4,16><<<gb3, 256, 0, stream>>>(off, csr, bufH, wbuf, b3, bufO, nullptr, Nn, 0);

  // mean pool + relu + linear + sigmoid + BCE loss
  hipMemsetAsync(pooled, 0, (size_t)Gg*48*4, stream);
  hipMemsetAsync(cntg, 0, (size_t)Gg*4, stream);
  hipMemsetAsync(lossAcc, 0, 4, stream);
  pool_cnt_k<<<(Nn + THREADS-1)/THREADS, THREADS, 0, stream>>>(batch, cntg, Nn);
  pool_acc_k<<<(Nn*48 + THREADS-1)/THREADS, THREADS, 0, stream>>>(bufO, batch, pooled, Nn);
  logits_k<<<(Gg + THREADS-1)/THREADS, THREADS, 0, stream>>>(pooled, cntg, Wl, bl, y, outp, lossAcc, Gg);
  fin_k<<<1, 1, 0, stream>>>(lossAcc, outp, Gg);
}